// Round 11
// baseline (1105.523 us; speedup 1.0000x reference)
//
#include <hip/hip_runtime.h>

// out = relu(x @ W1) @ W2
// x: [N,155] fp32, W1: [155,128] fp32, W2: [128,3] fp32, out: [N,3] fp32.
// v13: delete the x LDS round-trip entirely. Each lane loads its MFMA A
//      k-slice directly from global as dwordx4 pairs (16 contiguous rows per
//      wave, 8 lanes per 128B line -> sector-clean, ~1.0x fetch; v3's 1.6x
//      came from SCALAR dword loads), converts fp32->bf16 in-register, and
//      MFMAs against W1^T in LDS. LDS = W1^T + W2 only (44.5 KB) -> 2 blocks
//      /CU at 512 threads = 16 waves/CU (v9's occupancy) with ZERO loop
//      barriers, zero ds_writes, zero xs traffic: DS pipe (~65us, B-frags
//      only) now overlaps HBM (~103us) instead of alternating in barriered
//      phases (v9's 13.8k-cyc DS + 15.5k-cyc HBM per tile summed to 29.5k).
//      Grid 512 x 2048 rows: exactly 2 resident blocks/CU, W1 staged once.
//      k-tail handled OOB-free: quad 3's last slice loads cols 147..154 and
//      remaps slots (cols 152..154 + zeros); all addresses in-bounds.

#define N_TOTAL 1048576
#define IN_DIM 155
#define HIDDEN 128
#define BLOCK_THREADS 512
#define ROWS_PER_BLOCK 2048
#define SWEEP_ROWS 128  // 8 waves x 16 rows
#define NSWEEPS 16      // ROWS_PER_BLOCK / SWEEP_ROWS
#define XK 168          // LDS k-stride (bf16): 336B rows, conflict-free b128

typedef __attribute__((ext_vector_type(4), aligned(4))) float fvec4u;  // align-4 x4
typedef __attribute__((ext_vector_type(8))) short short8;   // 8 bf16 MFMA A/B frag
typedef __attribute__((ext_vector_type(4))) float floatx4;  // MFMA C/D frag

static __device__ __forceinline__ unsigned short f2bf(float f) {
  // round-to-nearest-even fp32 -> bf16 (inputs are finite normals; f2bf(0)=0)
  unsigned int u = __builtin_bit_cast(unsigned int, f);
  u += 0x7fffu + ((u >> 16) & 1u);
  return (unsigned short)(u >> 16);
}

// v += row_ror<N>(v): rotate within the 16-lane DPP row (VALU pipe, no DS op).
// ror 8,4,2,1 chain = full 16-lane sum in every lane. (validated v7-v12)
template <int CTRL>
static __device__ __forceinline__ float dpp_ror_add(float v) {
  const int m = __builtin_amdgcn_update_dpp(
      0, __builtin_bit_cast(int, v), CTRL, 0xf, 0xf, true);
  return v + __builtin_bit_cast(float, m);
}

__global__ __launch_bounds__(512, 4) void fused_mlp_kernel(
    const float* __restrict__ x, const float* __restrict__ W1,
    const float* __restrict__ W2, float* __restrict__ out) {
  __shared__ __align__(16) unsigned short w1s[HIDDEN * XK];  // 43008 B, W1^T bf16
  __shared__ __align__(16) float w2s[HIDDEN * 3];            // 1536 B

  const int tid = threadIdx.x;
  const int ln = tid & 15;
  const int quad = (tid >> 4) & 3;  // 16-lane group within the wave
  const int wave = tid >> 6;        // 0..7
  const int l = tid & 63;

  // ---- stage W1^T as bf16 into LDS (once per block; W1 is L2-hot) ----
  for (int idx = tid; idx < IN_DIM * HIDDEN; idx += BLOCK_THREADS) {
    const int k = idx >> 7;
    const int n = idx & 127;
    w1s[n * XK + k] = f2bf(W1[idx]);
  }
  for (int idx = tid; idx < HIDDEN * 16; idx += BLOCK_THREADS) {  // zero k-pad 155..167
    const int n = idx >> 4;
    const int k = 152 + (idx & 15);
    if (k >= IN_DIM) w1s[n * XK + k] = 0;
  }
  for (int idx = tid; idx < HIDDEN * 3; idx += BLOCK_THREADS) w2s[idx] = W2[idx];
  __syncthreads();  // the ONLY barrier: w1s/w2s are read-only below

  const size_t brow = (size_t)blockIdx.x * ROWS_PER_BLOCK;

  // epilogue routing: dst lane l (<48) pulls from src lane 16*(l/12) + (l%12)
  const int srcaddr = ((l / 12) * 16 + (l % 12)) << 2;

  for (int g = 0; g < NSWEEPS; ++g) {
    const size_t row0 = brow + (size_t)g * SWEEP_ROWS + wave * 16;
    const float* rp = x + (row0 + ln) * (size_t)IN_DIM;  // this lane's row

    // ---- load this lane's full k-slice: 10 x dwordx4, all in-bounds ----
    // s<4 or quad<3: cols s*32+quad*8 .. +7.  s==4,quad==3: cols 147..154
    // (slice would be 152..159; cols >=155 must be zero, so load shifted).
    fvec4u a[10];
#pragma unroll
    for (int s = 0; s < 5; ++s) {
      const int c0 = (s < 4 || quad < 3) ? (s * 32 + quad * 8) : 147;
      a[2 * s] = *reinterpret_cast<const fvec4u*>(rp + c0);
      a[2 * s + 1] = *reinterpret_cast<const fvec4u*>(rp + c0 + 4);
    }

    // ---- layer 1: in-register convert + MFMA, B-frags from LDS ----
    floatx4 acc[8];
#pragma unroll
    for (int c8 = 0; c8 < 8; ++c8) acc[c8] = (floatx4)0.f;
#pragma unroll
    for (int s = 0; s < 5; ++s) {
      const int kb = s * 32 + quad * 8;
      short8 af;
      if (s < 4) {
#pragma unroll
        for (int j = 0; j < 4; ++j) {
          af[j] = (short)f2bf(a[2 * s][j]);
          af[j + 4] = (short)f2bf(a[2 * s + 1][j]);
        }
      } else {
        // quads 0..2: straight cols 128+8q..+7 (all <155).
        // quad 3: a[9]=[151,152,153,154] -> slots [152,153,154,0,0,0,0,0].
        const bool q3 = (quad == 3);
        const float v0 = q3 ? (float)a[9][1] : (float)a[8][0];
        const float v1 = q3 ? (float)a[9][2] : (float)a[8][1];
        const float v2 = q3 ? (float)a[9][3] : (float)a[8][2];
        const float v3 = q3 ? 0.f : (float)a[8][3];
        const float v4 = q3 ? 0.f : (float)a[9][0];
        const float v5 = q3 ? 0.f : (float)a[9][1];
        const float v6 = q3 ? 0.f : (float)a[9][2];
        const float v7 = q3 ? 0.f : (float)a[9][3];
        af[0] = (short)f2bf(v0);
        af[1] = (short)f2bf(v1);
        af[2] = (short)f2bf(v2);
        af[3] = (short)f2bf(v3);
        af[4] = (short)f2bf(v4);
        af[5] = (short)f2bf(v5);
        af[6] = (short)f2bf(v6);
        af[7] = (short)f2bf(v7);
      }
#pragma unroll
      for (int t8 = 0; t8 < 8; ++t8) {
        const short8 b =
            *reinterpret_cast<const short8*>(&w1s[(t8 * 16 + ln) * XK + kb]);
        acc[t8] = __builtin_amdgcn_mfma_f32_16x16x32_bf16(af, b, acc[t8], 0, 0, 0);
      }
    }

    // ---- layer 2: relu + W2, reduce across 16-lane group ----
    // acc[t8][r] = h[row0 + quad*4 + r][16*t8 + ln]
    float part[4][3];
#pragma unroll
    for (int r = 0; r < 4; ++r)
#pragma unroll
      for (int c = 0; c < 3; ++c) part[r][c] = 0.f;
#pragma unroll
    for (int t8 = 0; t8 < 8; ++t8) {
      const float wa = w2s[(t8 * 16 + ln) * 3 + 0];
      const float wb = w2s[(t8 * 16 + ln) * 3 + 1];
      const float wc = w2s[(t8 * 16 + ln) * 3 + 2];
#pragma unroll
      for (int r = 0; r < 4; ++r) {
        const float hv = fmaxf(acc[t8][r], 0.f);
        part[r][0] = fmaf(hv, wa, part[r][0]);
        part[r][1] = fmaf(hv, wb, part[r][1]);
        part[r][2] = fmaf(hv, wc, part[r][2]);
      }
    }
    // full 16-lane reduce on DPP row_ror (VALU pipe; no DS ops, no conflicts)
#pragma unroll
    for (int r = 0; r < 4; ++r)
#pragma unroll
      for (int c = 0; c < 3; ++c) {
        float v = part[r][c];
        v = dpp_ror_add<0x128>(v);  // ror 8
        v = dpp_ror_add<0x124>(v);  // ror 4
        v = dpp_ror_add<0x122>(v);  // ror 2
        v = dpp_ror_add<0x121>(v);  // ror 1
        part[r][c] = v;
      }

    // ---- single coalesced 192B store per wave ----
    // lane j (j<12) of each 16-lane group selects part[j/3][j%3] (cndmask
    // tree), then dst lane l pulls from lane 16*(l/12) + (l%12).
    float v = part[0][0];
    v = (ln == 1) ? part[0][1] : v;
    v = (ln == 2) ? part[0][2] : v;
    v = (ln == 3) ? part[1][0] : v;
    v = (ln == 4) ? part[1][1] : v;
    v = (ln == 5) ? part[1][2] : v;
    v = (ln == 6) ? part[2][0] : v;
    v = (ln == 7) ? part[2][1] : v;
    v = (ln == 8) ? part[2][2] : v;
    v = (ln == 9) ? part[3][0] : v;
    v = (ln == 10) ? part[3][1] : v;
    v = (ln == 11) ? part[3][2] : v;
    const int vo = __builtin_amdgcn_ds_bpermute(srcaddr, __builtin_bit_cast(int, v));
    if (l < 48) out[row0 * 3 + l] = __builtin_bit_cast(float, vo);
  }
}

extern "C" void kernel_launch(void* const* d_in, const int* in_sizes, int n_in,
                              void* d_out, int out_size, void* d_ws, size_t ws_size,
                              hipStream_t stream) {
  const float* x = (const float*)d_in[0];
  const float* W1 = (const float*)d_in[1];
  const float* W2 = (const float*)d_in[2];
  float* out = (float*)d_out;
  fused_mlp_kernel<<<dim3(N_TOTAL / ROWS_PER_BLOCK), dim3(BLOCK_THREADS), 0, stream>>>(
      x, W1, W2, out);
}

// Round 12
// 858.235 us; speedup vs baseline: 1.2881x; 1.2881x over previous
//
#include <hip/hip_runtime.h>

// out = relu(x @ W1) @ W2
// x: [N,155] fp32, W1: [155,128] fp32, W2: [128,3] fp32, out: [N,3] fp32.
// v14: v13 with EXACTLY ONE change: __launch_bounds__(512, 4) -> (512, 2).
//      Cross-kernel VGPR_Count calibration ((256,3)->84, (256,1)->84,
//      (1024,4)->64, (512,4)->64) shows hipcc honors the 2nd arg as min
//      BLOCKS per CU (CUDA semantics): (512,4) = 32 waves/CU = 8 waves/SIMD
//      -> 64-VGPR budget, while v13 needs ~105 (a[10]=40 + acc[8]=32 +
//      epilogue) -> per-sweep scratch spill (WRITE_SIZE 130MB = 10x output,
//      FETCH 2.2x). (512,2) = 16 waves/CU = 4 waves/SIMD -> 128-VGPR cap,
//      which is also exactly the occupancy the kernel was designed for
//      (2 blocks/CU x 44.5 KB LDS). Everything else byte-identical to v13:
//      direct-global A-frags (no x LDS round-trip), zero loop barriers,
//      W1^T bf16 + W2 in LDS, DPP epilogue, coalesced 192B stores.

#define N_TOTAL 1048576
#define IN_DIM 155
#define HIDDEN 128
#define BLOCK_THREADS 512
#define ROWS_PER_BLOCK 2048
#define SWEEP_ROWS 128  // 8 waves x 16 rows
#define NSWEEPS 16      // ROWS_PER_BLOCK / SWEEP_ROWS
#define XK 168          // LDS k-stride (bf16): 336B rows, benign 2-way banks

typedef __attribute__((ext_vector_type(4), aligned(4))) float fvec4u;  // align-4 x4
typedef __attribute__((ext_vector_type(8))) short short8;   // 8 bf16 MFMA A/B frag
typedef __attribute__((ext_vector_type(4))) float floatx4;  // MFMA C/D frag

static __device__ __forceinline__ unsigned short f2bf(float f) {
  // round-to-nearest-even fp32 -> bf16 (inputs are finite normals; f2bf(0)=0)
  unsigned int u = __builtin_bit_cast(unsigned int, f);
  u += 0x7fffu + ((u >> 16) & 1u);
  return (unsigned short)(u >> 16);
}

// v += row_ror<N>(v): rotate within the 16-lane DPP row (VALU pipe, no DS op).
// ror 8,4,2,1 chain = full 16-lane sum in every lane. (validated v7-v13)
template <int CTRL>
static __device__ __forceinline__ float dpp_ror_add(float v) {
  const int m = __builtin_amdgcn_update_dpp(
      0, __builtin_bit_cast(int, v), CTRL, 0xf, 0xf, true);
  return v + __builtin_bit_cast(float, m);
}

__global__ __launch_bounds__(512, 2) void fused_mlp_kernel(
    const float* __restrict__ x, const float* __restrict__ W1,
    const float* __restrict__ W2, float* __restrict__ out) {
  __shared__ __align__(16) unsigned short w1s[HIDDEN * XK];  // 43008 B, W1^T bf16
  __shared__ __align__(16) float w2s[HIDDEN * 3];            // 1536 B

  const int tid = threadIdx.x;
  const int ln = tid & 15;
  const int quad = (tid >> 4) & 3;  // 16-lane group within the wave
  const int wave = tid >> 6;        // 0..7
  const int l = tid & 63;

  // ---- stage W1^T as bf16 into LDS (once per block; W1 is L2-hot) ----
  for (int idx = tid; idx < IN_DIM * HIDDEN; idx += BLOCK_THREADS) {
    const int k = idx >> 7;
    const int n = idx & 127;
    w1s[n * XK + k] = f2bf(W1[idx]);
  }
  for (int idx = tid; idx < HIDDEN * 16; idx += BLOCK_THREADS) {  // zero k-pad 155..167
    const int n = idx >> 4;
    const int k = 152 + (idx & 15);
    if (k >= IN_DIM) w1s[n * XK + k] = 0;
  }
  for (int idx = tid; idx < HIDDEN * 3; idx += BLOCK_THREADS) w2s[idx] = W2[idx];
  __syncthreads();  // the ONLY barrier: w1s/w2s are read-only below

  const size_t brow = (size_t)blockIdx.x * ROWS_PER_BLOCK;

  // epilogue routing: dst lane l (<48) pulls from src lane 16*(l/12) + (l%12)
  const int srcaddr = ((l / 12) * 16 + (l % 12)) << 2;

  for (int g = 0; g < NSWEEPS; ++g) {
    const size_t row0 = brow + (size_t)g * SWEEP_ROWS + wave * 16;
    const float* rp = x + (row0 + ln) * (size_t)IN_DIM;  // this lane's row

    // ---- load this lane's full k-slice: 10 x dwordx4, all in-bounds ----
    // s<4 or quad<3: cols s*32+quad*8 .. +7.  s==4,quad==3: cols 147..154
    // (slice would be 152..159; cols >=155 must be zero, so load shifted).
    fvec4u a[10];
#pragma unroll
    for (int s = 0; s < 5; ++s) {
      const int c0 = (s < 4 || quad < 3) ? (s * 32 + quad * 8) : 147;
      a[2 * s] = *reinterpret_cast<const fvec4u*>(rp + c0);
      a[2 * s + 1] = *reinterpret_cast<const fvec4u*>(rp + c0 + 4);
    }

    // ---- layer 1: in-register convert + MFMA, B-frags from LDS ----
    floatx4 acc[8];
#pragma unroll
    for (int c8 = 0; c8 < 8; ++c8) acc[c8] = (floatx4)0.f;
#pragma unroll
    for (int s = 0; s < 5; ++s) {
      const int kb = s * 32 + quad * 8;
      short8 af;
      if (s < 4) {
#pragma unroll
        for (int j = 0; j < 4; ++j) {
          af[j] = (short)f2bf(a[2 * s][j]);
          af[j + 4] = (short)f2bf(a[2 * s + 1][j]);
        }
      } else {
        // quads 0..2: straight cols 128+8q..+7 (all <155).
        // quad 3: a[9]=[151,152,153,154] -> slots [152,153,154,0,0,0,0,0].
        const bool q3 = (quad == 3);
        const float v0 = q3 ? (float)a[9][1] : (float)a[8][0];
        const float v1 = q3 ? (float)a[9][2] : (float)a[8][1];
        const float v2 = q3 ? (float)a[9][3] : (float)a[8][2];
        const float v3 = q3 ? 0.f : (float)a[8][3];
        const float v4 = q3 ? 0.f : (float)a[9][0];
        const float v5 = q3 ? 0.f : (float)a[9][1];
        const float v6 = q3 ? 0.f : (float)a[9][2];
        const float v7 = q3 ? 0.f : (float)a[9][3];
        af[0] = (short)f2bf(v0);
        af[1] = (short)f2bf(v1);
        af[2] = (short)f2bf(v2);
        af[3] = (short)f2bf(v3);
        af[4] = (short)f2bf(v4);
        af[5] = (short)f2bf(v5);
        af[6] = (short)f2bf(v6);
        af[7] = (short)f2bf(v7);
      }
#pragma unroll
      for (int t8 = 0; t8 < 8; ++t8) {
        const short8 b =
            *reinterpret_cast<const short8*>(&w1s[(t8 * 16 + ln) * XK + kb]);
        acc[t8] = __builtin_amdgcn_mfma_f32_16x16x32_bf16(af, b, acc[t8], 0, 0, 0);
      }
    }

    // ---- layer 2: relu + W2, reduce across 16-lane group ----
    // acc[t8][r] = h[row0 + quad*4 + r][16*t8 + ln]
    float part[4][3];
#pragma unroll
    for (int r = 0; r < 4; ++r)
#pragma unroll
      for (int c = 0; c < 3; ++c) part[r][c] = 0.f;
#pragma unroll
    for (int t8 = 0; t8 < 8; ++t8) {
      const float wa = w2s[(t8 * 16 + ln) * 3 + 0];
      const float wb = w2s[(t8 * 16 + ln) * 3 + 1];
      const float wc = w2s[(t8 * 16 + ln) * 3 + 2];
#pragma unroll
      for (int r = 0; r < 4; ++r) {
        const float hv = fmaxf(acc[t8][r], 0.f);
        part[r][0] = fmaf(hv, wa, part[r][0]);
        part[r][1] = fmaf(hv, wb, part[r][1]);
        part[r][2] = fmaf(hv, wc, part[r][2]);
      }
    }
    // full 16-lane reduce on DPP row_ror (VALU pipe; no DS ops, no conflicts)
#pragma unroll
    for (int r = 0; r < 4; ++r)
#pragma unroll
      for (int c = 0; c < 3; ++c) {
        float v = part[r][c];
        v = dpp_ror_add<0x128>(v);  // ror 8
        v = dpp_ror_add<0x124>(v);  // ror 4
        v = dpp_ror_add<0x122>(v);  // ror 2
        v = dpp_ror_add<0x121>(v);  // ror 1
        part[r][c] = v;
      }

    // ---- single coalesced 192B store per wave ----
    // lane j (j<12) of each 16-lane group selects part[j/3][j%3] (cndmask
    // tree), then dst lane l pulls from lane 16*(l/12) + (l%12).
    float v = part[0][0];
    v = (ln == 1) ? part[0][1] : v;
    v = (ln == 2) ? part[0][2] : v;
    v = (ln == 3) ? part[1][0] : v;
    v = (ln == 4) ? part[1][1] : v;
    v = (ln == 5) ? part[1][2] : v;
    v = (ln == 6) ? part[2][0] : v;
    v = (ln == 7) ? part[2][1] : v;
    v = (ln == 8) ? part[2][2] : v;
    v = (ln == 9) ? part[3][0] : v;
    v = (ln == 10) ? part[3][1] : v;
    v = (ln == 11) ? part[3][2] : v;
    const int vo = __builtin_amdgcn_ds_bpermute(srcaddr, __builtin_bit_cast(int, v));
    if (l < 48) out[row0 * 3 + l] = __builtin_bit_cast(float, vo);
  }
}

extern "C" void kernel_launch(void* const* d_in, const int* in_sizes, int n_in,
                              void* d_out, int out_size, void* d_ws, size_t ws_size,
                              hipStream_t stream) {
  const float* x = (const float*)d_in[0];
  const float* W1 = (const float*)d_in[1];
  const float* W2 = (const float*)d_in[2];
  float* out = (float*)d_out;
  fused_mlp_kernel<<<dim3(N_TOTAL / ROWS_PER_BLOCK), dim3(BLOCK_THREADS), 0, stream>>>(
      x, W1, W2, out);
}